// Round 9
// baseline (282.429 us; speedup 1.0000x reference)
//
#include <hip/hip_runtime.h>
#include <math.h>
#include <stdint.h>

#define T_TOTAL 2048
#define NB 16
#define D 256
#define T0 1696      // h buffer covers t in [1696, 2047]
#define TBUF 352
#define TSKIP 1952   // skip needed for t in [1952, 2047]
#define LOUT 96

typedef __bf16 bf16x8 __attribute__((ext_vector_type(8)));
typedef float f32x16 __attribute__((ext_vector_type(16)));

__device__ __forceinline__ void gload_lds16(const void* src, void* lds_dst) {
    auto g = (const __attribute__((address_space(1))) void*)(uintptr_t)src;
    auto l = (__attribute__((address_space(3))) void*)(uintptr_t)(
                 (uint32_t)(uintptr_t)lds_dst);
    __builtin_amdgcn_global_load_lds(g, l, 16, 0, 0);
}

// ---------------- fused weight prep + up-projection (one dispatch)
__global__ __launch_bounds__(256) void prep_up(
    const float* __restrict__ dil_w, const float* __restrict__ skip_w,
    const float* __restrict__ x_lag, const float* __restrict__ x_cov,
    const float* __restrict__ up_W, const float* __restrict__ up_b,
    __bf16* __restrict__ wT, __bf16* __restrict__ w2,
    float* __restrict__ hf, __bf16* __restrict__ hb)
{
    const int g0 = blockIdx.x * 256 + threadIdx.x;
    const int NT = 2048 * 256;

    for (int u = g0; u < 8 * 512 * 32; u += NT) {
        int j = u & 31;
        int cog = u >> 5;
        const float* src = dil_w + ((size_t)cog << 9) + (j << 4);
        float4 a = *(const float4*)(src);
        float4 b = *(const float4*)(src + 4);
        float4 c = *(const float4*)(src + 8);
        float4 d = *(const float4*)(src + 12);
        bf16x8 t0 = {(__bf16)a.x, (__bf16)a.z, (__bf16)b.x, (__bf16)b.z,
                     (__bf16)c.x, (__bf16)c.z, (__bf16)d.x, (__bf16)d.z};
        bf16x8 t1 = {(__bf16)a.y, (__bf16)a.w, (__bf16)b.y, (__bf16)b.w,
                     (__bf16)c.y, (__bf16)c.w, (__bf16)d.y, (__bf16)d.w};
        *(bf16x8*)(wT + ((size_t)cog << 9) + (j << 3)) = t0;
        *(bf16x8*)(wT + ((size_t)cog << 9) + 256 + (j << 3)) = t1;
    }
    for (int u = g0; u < 8 * 512 * 32; u += NT) {
        const float* src = skip_w + ((size_t)u << 3);
        float4 a = *(const float4*)(src);
        float4 b = *(const float4*)(src + 4);
        bf16x8 v = {(__bf16)a.x, (__bf16)a.y, (__bf16)a.z, (__bf16)a.w,
                    (__bf16)b.x, (__bf16)b.y, (__bf16)b.z, (__bf16)b.w};
        *(bf16x8*)(w2 + ((size_t)u << 3)) = v;
    }
    for (int u = g0; u < TBUF * NB * D; u += NT) {
        int row = u >> 8, c = u & 255;
        int tt = row >> 4, b = row & 15, t = T0 + tt;
        float acc = up_b[c] + x_lag[t * NB + b] * up_W[c];
        const float* cov = &x_cov[(t * NB + b) * 7];
        #pragma unroll
        for (int j = 0; j < 7; ++j)
            acc += cov[j] * up_W[(j + 1) * D + c];
        hf[u] = acc;
        hb[u] = (__bf16)acc;
    }
}

// ---------------- GEMM1 (32x32x16 MFMA, dbuf): z=[h(t-dil),h(t)]@wT^T
// grid (mt, 2); block 256 thr / 4 waves (1m x 4n); wave: 64 rows x (32f+32g)
__global__ __launch_bounds__(256, 2) void gate_v5(
    const __bf16* __restrict__ hb, __bf16* __restrict__ gated,
    const __bf16* __restrict__ wTl, const float* __restrict__ gbias,
    int tb, int dil, int M)
{
    __shared__ __align__(16) unsigned char lds[81920];  // 2 x (8K A + 16K Bf + 16K Bg)
    const int tid = threadIdx.x;
    const int lane = tid & 63, wid = tid >> 6;
    const int l31 = lane & 31, lh = lane >> 5;
    const int m0 = blockIdx.x << 6;
    const int cb = blockIdx.y << 7;               // 0 or 128
    const int swz = ((lane & 7) ^ (lane >> 3)) << 3;   // staging src elem off
    const int xk = (l31 & 7) << 4;                // read-side byte xor
    const int roff1 = (tb - T0) * 16;
    const int roff0 = roff1 - dil * 16;

    f32x16 accf0 = {}, accf1 = {}, accg0 = {}, accg1 = {};

    auto stage = [&](int t, int buf) {
        const int k0 = t << 6;
        const int ci0 = k0 & 255;
        const int roff = (t < 4) ? roff0 : roff1;
        unsigned char* base = lds + buf * 40960;
        #pragma unroll
        for (int j = 0; j < 2; ++j) {
            int q = (wid << 1) + j;               // 0..7 -> A rows q*8..
            int m = m0 + (q << 3) + (lane >> 3); if (m >= M) m = M - 1;
            gload_lds16(hb + (size_t)(m + roff) * 256 + ci0 + swz,
                        base + (q << 10));
        }
        #pragma unroll
        for (int j = 0; j < 4; ++j) {
            int q = (wid << 2) + j;               // 0..15 -> B rows q*8..
            int row = (q << 3) + (lane >> 3);
            gload_lds16(wTl + (size_t)(cb + row) * 512 + k0 + swz,
                        base + 8192 + (q << 10));
            gload_lds16(wTl + (size_t)(cb + 256 + row) * 512 + k0 + swz,
                        base + 24576 + (q << 10));
        }
    };

    stage(0, 0);
    for (int t = 0; t < 8; ++t) {
        const int buf = t & 1;
        if (t < 7) {
            stage(t + 1, buf ^ 1);
            asm volatile("s_waitcnt vmcnt(10)" ::: "memory");
        } else {
            asm volatile("s_waitcnt vmcnt(0)" ::: "memory");
        }
        __builtin_amdgcn_s_barrier();
        const unsigned char* base = lds + buf * 40960;
        const int rb = (wid << 5) + l31;
        __builtin_amdgcn_s_setprio(1);
        #pragma unroll
        for (int ks = 0; ks < 4; ++ks) {
            const int ko = ((ks << 5) + (lh << 4)) ^ xk;
            bf16x8 a0 = *(const bf16x8*)(base + l31 * 128 + ko);
            bf16x8 a1 = *(const bf16x8*)(base + (l31 + 32) * 128 + ko);
            bf16x8 bf = *(const bf16x8*)(base + 8192 + rb * 128 + ko);
            bf16x8 bg = *(const bf16x8*)(base + 24576 + rb * 128 + ko);
            accf0 = __builtin_amdgcn_mfma_f32_32x32x16_bf16(a0, bf, accf0, 0, 0, 0);
            accf1 = __builtin_amdgcn_mfma_f32_32x32x16_bf16(a1, bf, accf1, 0, 0, 0);
            accg0 = __builtin_amdgcn_mfma_f32_32x32x16_bf16(a0, bg, accg0, 0, 0, 0);
            accg1 = __builtin_amdgcn_mfma_f32_32x32x16_bf16(a1, bg, accg1, 0, 0, 0);
        }
        __builtin_amdgcn_s_setprio(0);
        __builtin_amdgcn_s_barrier();
    }

    const int c = cb + (wid << 5) + l31;
    const float bfb = gbias[c], bgb = gbias[c + 256];
    #pragma unroll
    for (int r = 0; r < 16; ++r) {
        int m = m0 + (r & 3) + ((r >> 2) << 3) + (lh << 2);
        if (m < M) {
            float fv = accf0[r] + bfb;
            float gv = accg0[r] + bgb;
            float th = 2.0f / (1.0f + __expf(-2.0f * fv)) - 1.0f;
            float sg = 1.0f / (1.0f + __expf(-gv));
            gated[(size_t)m * 256 + c] = (__bf16)(th * sg);
        }
    }
    #pragma unroll
    for (int r = 0; r < 16; ++r) {
        int m = m0 + 32 + (r & 3) + ((r >> 2) << 3) + (lh << 2);
        if (m < M) {
            float fv = accf1[r] + bfb;
            float gv = accg1[r] + bgb;
            float th = 2.0f / (1.0f + __expf(-2.0f * fv)) - 1.0f;
            float sg = 1.0f / (1.0f + __expf(-gv));
            gated[(size_t)m * 256 + c] = (__bf16)(th * sg);
        }
    }
}

// ---------------- GEMM2 (32x32x16 MFMA, dbuf, tail-aware): z2 = gated @ w2^T
__global__ __launch_bounds__(256, 2) void skip_v5(
    const __bf16* __restrict__ gated, const __bf16* __restrict__ w2l,
    float* __restrict__ hf, __bf16* __restrict__ hb,
    float* __restrict__ skip, const float* __restrict__ sbias,
    int tb, int M, int first)
{
    __shared__ __align__(16) unsigned char lds[81920];
    const int tid = threadIdx.x;
    const int lane = tid & 63, wid = tid >> 6;
    const int l31 = lane & 31, lh = lane >> 5;
    const int m0 = blockIdx.x << 6;
    const int cb = blockIdx.y << 7;
    const int swz = ((lane & 7) ^ (lane >> 3)) << 3;
    const int xk = (l31 & 7) << 4;
    const int roff1 = (tb - T0) * 16;
    const int ms0 = (TSKIP - tb) * 16;
    const bool do_s = (m0 + 64 > ms0);            // block-uniform

    f32x16 acch0 = {}, acch1 = {}, accs0 = {}, accs1 = {};

    auto stage = [&](int t, int buf) {
        const int k0 = t << 6;
        unsigned char* base = lds + buf * 40960;
        #pragma unroll
        for (int j = 0; j < 2; ++j) {
            int q = (wid << 1) + j;
            int m = m0 + (q << 3) + (lane >> 3); if (m >= M) m = M - 1;
            gload_lds16(gated + (size_t)m * 256 + k0 + swz,
                        base + (q << 10));
        }
        #pragma unroll
        for (int j = 0; j < 4; ++j) {
            int q = (wid << 2) + j;
            int row = (q << 3) + (lane >> 3);
            gload_lds16(w2l + (size_t)(cb + row) * 256 + k0 + swz,
                        base + 8192 + (q << 10));
            if (do_s)
                gload_lds16(w2l + (size_t)(cb + 256 + row) * 256 + k0 + swz,
                            base + 24576 + (q << 10));
        }
    };

    stage(0, 0);
    for (int t = 0; t < 4; ++t) {
        const int buf = t & 1;
        if (t < 3) {
            stage(t + 1, buf ^ 1);
            if (do_s) { asm volatile("s_waitcnt vmcnt(10)" ::: "memory"); }
            else      { asm volatile("s_waitcnt vmcnt(6)" ::: "memory"); }
        } else {
            asm volatile("s_waitcnt vmcnt(0)" ::: "memory");
        }
        __builtin_amdgcn_s_barrier();
        const unsigned char* base = lds + buf * 40960;
        const int rb = (wid << 5) + l31;
        __builtin_amdgcn_s_setprio(1);
        #pragma unroll
        for (int ks = 0; ks < 4; ++ks) {
            const int ko = ((ks << 5) + (lh << 4)) ^ xk;
            bf16x8 a0 = *(const bf16x8*)(base + l31 * 128 + ko);
            bf16x8 a1 = *(const bf16x8*)(base + (l31 + 32) * 128 + ko);
            bf16x8 bh = *(const bf16x8*)(base + 8192 + rb * 128 + ko);
            acch0 = __builtin_amdgcn_mfma_f32_32x32x16_bf16(a0, bh, acch0, 0, 0, 0);
            acch1 = __builtin_amdgcn_mfma_f32_32x32x16_bf16(a1, bh, acch1, 0, 0, 0);
            if (do_s) {
                bf16x8 bs = *(const bf16x8*)(base + 24576 + rb * 128 + ko);
                accs0 = __builtin_amdgcn_mfma_f32_32x32x16_bf16(a0, bs, accs0, 0, 0, 0);
                accs1 = __builtin_amdgcn_mfma_f32_32x32x16_bf16(a1, bs, accs1, 0, 0, 0);
            }
        }
        __builtin_amdgcn_s_setprio(0);
        __builtin_amdgcn_s_barrier();
    }

    const int soff = (tb - TSKIP) * 16;
    const int c = cb + (wid << 5) + l31;
    const float bhb = sbias[c], bsb = sbias[c + 256];
    #pragma unroll
    for (int r = 0; r < 16; ++r) {
        int m = m0 + (r & 3) + ((r >> 2) << 3) + (lh << 2);
        if (m < M) {
            size_t hi = (size_t)(m + roff1) * 256 + c;
            float hv = hf[hi] + acch0[r] + bhb;
            hf[hi] = hv;
            hb[hi] = (__bf16)hv;
            if (do_s && m >= ms0) {
                size_t si = (size_t)(m + soff) * 256 + c;
                float sv = accs0[r] + bsb;
                if (!first) sv += skip[si];
                skip[si] = sv;
            }
        }
    }
    #pragma unroll
    for (int r = 0; r < 16; ++r) {
        int m = m0 + 32 + (r & 3) + ((r >> 2) << 3) + (lh << 2);
        if (m < M) {
            size_t hi = (size_t)(m + roff1) * 256 + c;
            float hv = hf[hi] + acch1[r] + bhb;
            hf[hi] = hv;
            hb[hi] = (__bf16)hv;
            if (do_s && m >= ms0) {
                size_t si = (size_t)(m + soff) * 256 + c;
                float sv = accs1[r] + bsb;
                if (!first) sv += skip[si];
                skip[si] = sv;
            }
        }
    }
}

// ---------------- final
__global__ void final_kernel(const float* __restrict__ skip,
                             const float* __restrict__ loc_W,
                             const float* __restrict__ loc_b,
                             const float* __restrict__ proj_W,
                             const float* __restrict__ proj_b,
                             float* __restrict__ out)
{
    int tid = threadIdx.x;
    int w = tid >> 6, lane = tid & 63;
    int o = blockIdx.x * 4 + w;          // o = l*16 + b
    int l = o >> 4, b = o & 15;
    float4 s4 = *(const float4*)&skip[((size_t)o << 8) + (lane << 2)];
    float4 w4 = *(const float4*)&loc_W[lane << 2];
    float s = s4.x * w4.x + s4.y * w4.y + s4.z * w4.z + s4.w * w4.w;
    #pragma unroll
    for (int off = 32; off; off >>= 1) s += __shfl_down(s, off);
    if (lane == 0)
        out[b * LOUT + l] = (s + loc_b[0]) * proj_W[0] + proj_b[0];
}

extern "C" void kernel_launch(void* const* d_in, const int* in_sizes, int n_in,
                              void* d_out, int out_size, void* d_ws, size_t ws_size,
                              hipStream_t stream)
{
    const float* x_lag  = (const float*)d_in[0];
    const float* x_cov  = (const float*)d_in[1];
    const float* up_W   = (const float*)d_in[2];
    const float* up_b   = (const float*)d_in[3];
    const float* dil_w  = (const float*)d_in[4];
    const float* dil_b  = (const float*)d_in[5];
    const float* skip_w = (const float*)d_in[6];
    const float* skip_b = (const float*)d_in[7];
    const float* loc_W  = (const float*)d_in[8];
    const float* loc_b  = (const float*)d_in[9];
    const float* proj_W = (const float*)d_in[10];
    const float* proj_b = (const float*)d_in[11];
    float* out = (float*)d_out;

    unsigned char* ws = (unsigned char*)d_ws;
    float*  hf   = (float*)ws;                              // 5632*256 f32
    __bf16* hb   = (__bf16*)(ws + 5767168);                 // 5632*256 bf16
    __bf16* gated= (__bf16*)(ws + 5767168 + 2883584);       // 5632*256 bf16
    float*  skip = (float*)(ws + 5767168 + 2 * 2883584);    // 1536*256 f32
    __bf16* wT   = (__bf16*)(ws + 5767168 + 2 * 2883584 + 1572864);  // 8*512*512
    __bf16* w2   = (__bf16*)((unsigned char*)wT + 4194304); // 8*512*256

    hipLaunchKernelGGL(prep_up, dim3(2048), dim3(256), 0, stream,
                       dil_w, skip_w, x_lag, x_cov, up_W, up_b, wT, w2, hf, hb);

    for (int i = 0; i < 8; ++i) {
        int dil = 1 << i;
        int tb  = T0 + 2 * dil;
        int M   = (T_TOTAL - tb) * NB;
        int mt  = (M + 63) >> 6;
        hipLaunchKernelGGL(gate_v5, dim3(mt, 2), dim3(256), 0, stream,
                           hb, gated, wT + (size_t)i * 512 * 512,
                           dil_b + (size_t)i * 512, tb, dil, M);
        hipLaunchKernelGGL(skip_v5, dim3(mt, 2), dim3(256), 0, stream,
                           gated, w2 + (size_t)i * 512 * 256, hf, hb, skip,
                           skip_b + (size_t)i * 512, tb, M, i == 0 ? 1 : 0);
    }
    hipLaunchKernelGGL(final_kernel, dim3(LOUT * NB / 4), dim3(256), 0, stream,
                       skip, loc_W, loc_b, proj_W, proj_b, out);
}

// Round 10
// 162.496 us; speedup vs baseline: 1.7381x; 1.7381x over previous
//
#include <hip/hip_runtime.h>
#include <math.h>
#include <stdint.h>

#define T_TOTAL 2048
#define NB 16
#define D 256
#define T0 1696      // h buffer covers t in [1696, 2047]
#define TBUF 352
#define TSKIP 1952   // skip needed for t in [1952, 2047]
#define LOUT 96

typedef __bf16 bf16x8 __attribute__((ext_vector_type(8)));
typedef float f32x4 __attribute__((ext_vector_type(4)));

__device__ __forceinline__ void gload_lds16(const void* src, void* lds_dst) {
    auto g = (const __attribute__((address_space(1))) void*)(uintptr_t)src;
    auto l = (__attribute__((address_space(3))) void*)(uintptr_t)(
                 (uint32_t)(uintptr_t)lds_dst);
    __builtin_amdgcn_global_load_lds(g, l, 16, 0, 0);
}

// ---------------- fused weight prep + up-projection (one dispatch)
__global__ __launch_bounds__(256) void prep_up(
    const float* __restrict__ dil_w, const float* __restrict__ skip_w,
    const float* __restrict__ x_lag, const float* __restrict__ x_cov,
    const float* __restrict__ up_W, const float* __restrict__ up_b,
    __bf16* __restrict__ wT, __bf16* __restrict__ w2,
    float* __restrict__ hf, __bf16* __restrict__ hb)
{
    const int g0 = blockIdx.x * 256 + threadIdx.x;
    const int NT = 2048 * 256;

    for (int u = g0; u < 8 * 512 * 32; u += NT) {
        int j = u & 31;
        int cog = u >> 5;
        const float* src = dil_w + ((size_t)cog << 9) + (j << 4);
        float4 a = *(const float4*)(src);
        float4 b = *(const float4*)(src + 4);
        float4 c = *(const float4*)(src + 8);
        float4 d = *(const float4*)(src + 12);
        bf16x8 t0 = {(__bf16)a.x, (__bf16)a.z, (__bf16)b.x, (__bf16)b.z,
                     (__bf16)c.x, (__bf16)c.z, (__bf16)d.x, (__bf16)d.z};
        bf16x8 t1 = {(__bf16)a.y, (__bf16)a.w, (__bf16)b.y, (__bf16)b.w,
                     (__bf16)c.y, (__bf16)c.w, (__bf16)d.y, (__bf16)d.w};
        *(bf16x8*)(wT + ((size_t)cog << 9) + (j << 3)) = t0;
        *(bf16x8*)(wT + ((size_t)cog << 9) + 256 + (j << 3)) = t1;
    }
    for (int u = g0; u < 8 * 512 * 32; u += NT) {
        const float* src = skip_w + ((size_t)u << 3);
        float4 a = *(const float4*)(src);
        float4 b = *(const float4*)(src + 4);
        bf16x8 v = {(__bf16)a.x, (__bf16)a.y, (__bf16)a.z, (__bf16)a.w,
                    (__bf16)b.x, (__bf16)b.y, (__bf16)b.z, (__bf16)b.w};
        *(bf16x8*)(w2 + ((size_t)u << 3)) = v;
    }
    for (int u = g0; u < TBUF * NB * D; u += NT) {
        int row = u >> 8, c = u & 255;
        int tt = row >> 4, b = row & 15, t = T0 + tt;
        float acc = up_b[c] + x_lag[t * NB + b] * up_W[c];
        const float* cov = &x_cov[(t * NB + b) * 7];
        #pragma unroll
        for (int j = 0; j < 7; ++j)
            acc += cov[j] * up_W[(j + 1) * D + c];
        hf[u] = acc;
        hb[u] = (__bf16)acc;
    }
}

// ---------------- GEMM1 (3-buf, 1-barrier/step): z=[h(t-dil),h(t)]@wT^T
// grid (mt, 4); block 512 thr / 8 waves; wave tile 32 rows x (16f + 16g)
__global__ __launch_bounds__(512, 4) void gate_v6(
    const __bf16* __restrict__ hb, __bf16* __restrict__ gated,
    const __bf16* __restrict__ wTl, const float* __restrict__ gbias,
    int tb, int dil, int M)
{
    __shared__ __align__(16) unsigned char lds[73728];   // 3 x 24KB
    const int tid = threadIdx.x;
    const int lane = tid & 63, wid = tid >> 6;
    const int wm = wid >> 2, wn = wid & 3;
    const int l15 = lane & 15, l4 = lane >> 4;
    const int m0 = blockIdx.x << 6;
    const int cb = blockIdx.y << 6;
    const int row_s = (wid << 3) + (lane >> 3);      // staging row 0..63
    const int swz = ((lane & 7) ^ (row_s & 7)) << 3; // swizzled src elem off
    const int roff1 = (tb - T0) * 16;
    const int roff0 = roff1 - dil * 16;

    f32x4 accf[2] = {}, accg[2] = {};

    auto stage = [&](int tt, int buf) {
        const int k0 = tt << 6;
        const int ci0 = k0 & 255;
        const int roff = (tt < 4) ? roff0 : roff1;
        unsigned char* base = lds + buf * 24576;
        int m = m0 + row_s; if (m >= M) m = M - 1;
        gload_lds16(hb + (size_t)(m + roff) * 256 + ci0 + swz,
                    base + (wid << 10));
        gload_lds16(wTl + (size_t)(cb + row_s) * 512 + k0 + swz,
                    base + 8192 + (wid << 10));
        gload_lds16(wTl + (size_t)(cb + 256 + row_s) * 512 + k0 + swz,
                    base + 16384 + (wid << 10));
    };

    stage(0, 0);
    stage(1, 1);
    #pragma unroll
    for (int t = 0; t < 8; ++t) {
        if (t < 7) { asm volatile("s_waitcnt vmcnt(3)" ::: "memory"); }
        else       { asm volatile("s_waitcnt vmcnt(0)" ::: "memory"); }
        __builtin_amdgcn_s_barrier();
        if (t < 6) stage(t + 2, (t + 2) % 3);
        const unsigned char* base = lds + (t % 3) * 24576;
        __builtin_amdgcn_s_setprio(1);
        #pragma unroll
        for (int ks = 0; ks < 2; ++ks) {
            const int kb = (ks << 6) + (l4 << 4);
            bf16x8 av[2], bfv, bgv;
            #pragma unroll
            for (int fm = 0; fm < 2; ++fm) {
                int r = (wm << 5) + (fm << 4) + l15;
                av[fm] = *(const bf16x8*)(base + r * 128 + (kb ^ ((r & 7) << 4)));
            }
            {
                int n = (wn << 4) + l15;
                int o = n * 128 + (kb ^ ((n & 7) << 4));
                bfv = *(const bf16x8*)(base + 8192 + o);
                bgv = *(const bf16x8*)(base + 16384 + o);
            }
            #pragma unroll
            for (int fm = 0; fm < 2; ++fm) {
                accf[fm] = __builtin_amdgcn_mfma_f32_16x16x32_bf16(
                    av[fm], bfv, accf[fm], 0, 0, 0);
                accg[fm] = __builtin_amdgcn_mfma_f32_16x16x32_bf16(
                    av[fm], bgv, accg[fm], 0, 0, 0);
            }
        }
        __builtin_amdgcn_s_setprio(0);
    }

    {
        int c = cb + (wn << 4) + l15;
        float bfb = gbias[c], bgb = gbias[c + 256];
        #pragma unroll
        for (int fm = 0; fm < 2; ++fm)
            #pragma unroll
            for (int r = 0; r < 4; ++r) {
                int m = m0 + (wm << 5) + (fm << 4) + (l4 << 2) + r;
                if (m < M) {
                    float fv = accf[fm][r] + bfb;
                    float gv = accg[fm][r] + bgb;
                    float th = 2.0f / (1.0f + __expf(-2.0f * fv)) - 1.0f;
                    float sg = 1.0f / (1.0f + __expf(-gv));
                    gated[(size_t)m * 256 + c] = (__bf16)(th * sg);
                }
            }
    }
}

// ---------------- GEMM2 (3-buf, 1-barrier/step, tail-aware): z2 = gated @ w2^T
// do_h: update h (all layers but last); do_s: accumulate skip (tail blocks)
__global__ __launch_bounds__(512, 4) void skip_v6(
    const __bf16* __restrict__ gated, const __bf16* __restrict__ w2l,
    float* __restrict__ hf, __bf16* __restrict__ hb,
    float* __restrict__ skip, const float* __restrict__ sbias,
    int tb, int M, int first, int do_h)
{
    __shared__ __align__(16) unsigned char lds[73728];
    const int tid = threadIdx.x;
    const int lane = tid & 63, wid = tid >> 6;
    const int wm = wid >> 2, wn = wid & 3;
    const int l15 = lane & 15, l4 = lane >> 4;
    const int m0 = blockIdx.x << 6;
    const int cb = blockIdx.y << 6;
    const int row_s = (wid << 3) + (lane >> 3);
    const int swz = ((lane & 7) ^ (row_s & 7)) << 3;
    const int roff1 = (tb - T0) * 16;
    const int ms0 = (TSKIP - tb) * 16;
    const bool do_s = (m0 + 64 > ms0);    // block-uniform
    const bool l3 = do_h && do_s;         // 3 loads/stage else 2

    f32x4 acch[2] = {}, accs[2] = {};

    auto stage = [&](int tt, int buf) {
        const int k0 = tt << 6;
        unsigned char* base = lds + buf * 24576;
        int m = m0 + row_s; if (m >= M) m = M - 1;
        gload_lds16(gated + (size_t)m * 256 + k0 + swz,
                    base + (wid << 10));
        if (do_h)
            gload_lds16(w2l + (size_t)(cb + row_s) * 256 + k0 + swz,
                        base + 8192 + (wid << 10));
        if (do_s)
            gload_lds16(w2l + (size_t)(cb + 256 + row_s) * 256 + k0 + swz,
                        base + 16384 + (wid << 10));
    };

    stage(0, 0);
    stage(1, 1);
    #pragma unroll
    for (int t = 0; t < 4; ++t) {
        if (t < 3) {
            if (l3) { asm volatile("s_waitcnt vmcnt(3)" ::: "memory"); }
            else    { asm volatile("s_waitcnt vmcnt(2)" ::: "memory"); }
        } else      { asm volatile("s_waitcnt vmcnt(0)" ::: "memory"); }
        __builtin_amdgcn_s_barrier();
        if (t < 2) stage(t + 2, (t + 2) % 3);
        const unsigned char* base = lds + (t % 3) * 24576;
        __builtin_amdgcn_s_setprio(1);
        #pragma unroll
        for (int ks = 0; ks < 2; ++ks) {
            const int kb = (ks << 6) + (l4 << 4);
            bf16x8 av[2];
            #pragma unroll
            for (int fm = 0; fm < 2; ++fm) {
                int r = (wm << 5) + (fm << 4) + l15;
                av[fm] = *(const bf16x8*)(base + r * 128 + (kb ^ ((r & 7) << 4)));
            }
            int n = (wn << 4) + l15;
            int o = n * 128 + (kb ^ ((n & 7) << 4));
            if (do_h) {
                bf16x8 bhv = *(const bf16x8*)(base + 8192 + o);
                #pragma unroll
                for (int fm = 0; fm < 2; ++fm)
                    acch[fm] = __builtin_amdgcn_mfma_f32_16x16x32_bf16(
                        av[fm], bhv, acch[fm], 0, 0, 0);
            }
            if (do_s) {
                bf16x8 bsv = *(const bf16x8*)(base + 16384 + o);
                #pragma unroll
                for (int fm = 0; fm < 2; ++fm)
                    accs[fm] = __builtin_amdgcn_mfma_f32_16x16x32_bf16(
                        av[fm], bsv, accs[fm], 0, 0, 0);
            }
        }
        __builtin_amdgcn_s_setprio(0);
    }

    const int soff = (tb - TSKIP) * 16;
    {
        int c = cb + (wn << 4) + l15;
        float bhb = sbias[c], bsb = sbias[c + 256];
        #pragma unroll
        for (int fm = 0; fm < 2; ++fm)
            #pragma unroll
            for (int r = 0; r < 4; ++r) {
                int m = m0 + (wm << 5) + (fm << 4) + (l4 << 2) + r;
                if (m < M) {
                    if (do_h) {
                        size_t hi = (size_t)(m + roff1) * 256 + c;
                        float hv = hf[hi] + acch[fm][r] + bhb;
                        hf[hi] = hv;
                        hb[hi] = (__bf16)hv;
                    }
                    if (do_s && m >= ms0) {
                        size_t si = (size_t)(m + soff) * 256 + c;
                        float sv = accs[fm][r] + bsb;
                        if (!first) sv += skip[si];
                        skip[si] = sv;
                    }
                }
            }
    }
}

// ---------------- final
__global__ void final_kernel(const float* __restrict__ skip,
                             const float* __restrict__ loc_W,
                             const float* __restrict__ loc_b,
                             const float* __restrict__ proj_W,
                             const float* __restrict__ proj_b,
                             float* __restrict__ out)
{
    int tid = threadIdx.x;
    int w = tid >> 6, lane = tid & 63;
    int o = blockIdx.x * 4 + w;          // o = l*16 + b
    int l = o >> 4, b = o & 15;
    float4 s4 = *(const float4*)&skip[((size_t)o << 8) + (lane << 2)];
    float4 w4 = *(const float4*)&loc_W[lane << 2];
    float s = s4.x * w4.x + s4.y * w4.y + s4.z * w4.z + s4.w * w4.w;
    #pragma unroll
    for (int off = 32; off; off >>= 1) s += __shfl_down(s, off);
    if (lane == 0)
        out[b * LOUT + l] = (s + loc_b[0]) * proj_W[0] + proj_b[0];
}

extern "C" void kernel_launch(void* const* d_in, const int* in_sizes, int n_in,
                              void* d_out, int out_size, void* d_ws, size_t ws_size,
                              hipStream_t stream)
{
    const float* x_lag  = (const float*)d_in[0];
    const float* x_cov  = (const float*)d_in[1];
    const float* up_W   = (const float*)d_in[2];
    const float* up_b   = (const float*)d_in[3];
    const float* dil_w  = (const float*)d_in[4];
    const float* dil_b  = (const float*)d_in[5];
    const float* skip_w = (const float*)d_in[6];
    const float* skip_b = (const float*)d_in[7];
    const float* loc_W  = (const float*)d_in[8];
    const float* loc_b  = (const float*)d_in[9];
    const float* proj_W = (const float*)d_in[10];
    const float* proj_b = (const float*)d_in[11];
    float* out = (float*)d_out;

    unsigned char* ws = (unsigned char*)d_ws;
    float*  hf   = (float*)ws;                              // 5632*256 f32
    __bf16* hb   = (__bf16*)(ws + 5767168);                 // 5632*256 bf16
    __bf16* gated= (__bf16*)(ws + 5767168 + 2883584);       // 5632*256 bf16
    float*  skip = (float*)(ws + 5767168 + 2 * 2883584);    // 1536*256 f32
    __bf16* wT   = (__bf16*)(ws + 5767168 + 2 * 2883584 + 1572864);  // 8*512*512
    __bf16* w2   = (__bf16*)((unsigned char*)wT + 4194304); // 8*512*256

    hipLaunchKernelGGL(prep_up, dim3(2048), dim3(256), 0, stream,
                       dil_w, skip_w, x_lag, x_cov, up_W, up_b, wT, w2, hf, hb);

    for (int i = 0; i < 8; ++i) {
        int dil = 1 << i;
        int tb  = T0 + 2 * dil;
        int M   = (T_TOTAL - tb) * NB;
        int mt  = (M + 63) >> 6;
        hipLaunchKernelGGL(gate_v6, dim3(mt, 4), dim3(512), 0, stream,
                           hb, gated, wT + (size_t)i * 512 * 512,
                           dil_b + (size_t)i * 512, tb, dil, M);
        hipLaunchKernelGGL(skip_v6, dim3(mt, 4), dim3(512), 0, stream,
                           gated, w2 + (size_t)i * 512 * 256, hf, hb, skip,
                           skip_b + (size_t)i * 512, tb, M,
                           i == 0 ? 1 : 0, i == 7 ? 0 : 1);
    }
    hipLaunchKernelGGL(final_kernel, dim3(LOUT * NB / 4), dim3(256), 0, stream,
                       skip, loc_W, loc_b, proj_W, proj_b, out);
}

// Round 11
// 158.334 us; speedup vs baseline: 1.7838x; 1.0263x over previous
//
#include <hip/hip_runtime.h>
#include <math.h>
#include <stdint.h>

#define T_TOTAL 2048
#define NB 16
#define D 256
#define T0 1696      // h buffer covers t in [1696, 2047]
#define TBUF 352
#define TSKIP 1952   // skip needed for t in [1952, 2047]
#define LOUT 96

typedef __bf16 bf16x8 __attribute__((ext_vector_type(8)));
typedef float f32x4 __attribute__((ext_vector_type(4)));

__device__ __forceinline__ void gload_lds16(const void* src, void* lds_dst) {
    auto g = (const __attribute__((address_space(1))) void*)(uintptr_t)src;
    auto l = (__attribute__((address_space(3))) void*)(uintptr_t)(
                 (uint32_t)(uintptr_t)lds_dst);
    __builtin_amdgcn_global_load_lds(g, l, 16, 0, 0);
}

// ---------------- fused weight prep + up-projection (one dispatch)
__global__ __launch_bounds__(256) void prep_up(
    const float* __restrict__ dil_w, const float* __restrict__ skip_w,
    const float* __restrict__ x_lag, const float* __restrict__ x_cov,
    const float* __restrict__ up_W, const float* __restrict__ up_b,
    __bf16* __restrict__ wT, __bf16* __restrict__ w2,
    float* __restrict__ hf, __bf16* __restrict__ hb)
{
    const int g0 = blockIdx.x * 256 + threadIdx.x;
    const int NT = 2048 * 256;

    for (int u = g0; u < 8 * 512 * 32; u += NT) {
        int j = u & 31;
        int cog = u >> 5;
        const float* src = dil_w + ((size_t)cog << 9) + (j << 4);
        float4 a = *(const float4*)(src);
        float4 b = *(const float4*)(src + 4);
        float4 c = *(const float4*)(src + 8);
        float4 d = *(const float4*)(src + 12);
        bf16x8 t0 = {(__bf16)a.x, (__bf16)a.z, (__bf16)b.x, (__bf16)b.z,
                     (__bf16)c.x, (__bf16)c.z, (__bf16)d.x, (__bf16)d.z};
        bf16x8 t1 = {(__bf16)a.y, (__bf16)a.w, (__bf16)b.y, (__bf16)b.w,
                     (__bf16)c.y, (__bf16)c.w, (__bf16)d.y, (__bf16)d.w};
        *(bf16x8*)(wT + ((size_t)cog << 9) + (j << 3)) = t0;
        *(bf16x8*)(wT + ((size_t)cog << 9) + 256 + (j << 3)) = t1;
    }
    for (int u = g0; u < 8 * 512 * 32; u += NT) {
        const float* src = skip_w + ((size_t)u << 3);
        float4 a = *(const float4*)(src);
        float4 b = *(const float4*)(src + 4);
        bf16x8 v = {(__bf16)a.x, (__bf16)a.y, (__bf16)a.z, (__bf16)a.w,
                    (__bf16)b.x, (__bf16)b.y, (__bf16)b.z, (__bf16)b.w};
        *(bf16x8*)(w2 + ((size_t)u << 3)) = v;
    }
    for (int u = g0; u < TBUF * NB * D; u += NT) {
        int row = u >> 8, c = u & 255;
        int tt = row >> 4, b = row & 15, t = T0 + tt;
        float acc = up_b[c] + x_lag[t * NB + b] * up_W[c];
        const float* cov = &x_cov[(t * NB + b) * 7];
        #pragma unroll
        for (int j = 0; j < 7; ++j)
            acc += cov[j] * up_W[(j + 1) * D + c];
        hf[u] = acc;
        hb[u] = (__bf16)acc;
    }
}

// ---------------- GEMM1 big (r8): grid (mt,4), 512 thr, wave 32r x (16f+16g)
__global__ __launch_bounds__(512, 4) void gate_v4(
    const __bf16* __restrict__ hb, __bf16* __restrict__ gated,
    const __bf16* __restrict__ wTl, const float* __restrict__ gbias,
    int tb, int dil, int M)
{
    __shared__ __align__(16) unsigned char lds[49152];
    const int tid = threadIdx.x;
    const int lane = tid & 63, wid = tid >> 6;
    const int wm = wid >> 2, wn = wid & 3;
    const int l15 = lane & 15, l4 = lane >> 4;
    const int m0 = blockIdx.x << 6;
    const int cb = blockIdx.y << 6;
    const int row_s = (wid << 3) + (lane >> 3);
    const int swz = ((lane & 7) ^ (row_s & 7)) << 3;
    const int roff1 = (tb - T0) * 16;
    const int roff0 = roff1 - dil * 16;

    f32x4 accf[2] = {}, accg[2] = {};

    auto stage = [&](int t, int buf) {
        const int k0 = t << 6;
        const int ci0 = k0 & 255;
        const int roff = (t < 4) ? roff0 : roff1;
        unsigned char* base = lds + buf * 24576;
        int m = m0 + row_s; if (m >= M) m = M - 1;
        gload_lds16(hb + (size_t)(m + roff) * 256 + ci0 + swz,
                    base + (wid << 10));
        gload_lds16(wTl + (size_t)(cb + row_s) * 512 + k0 + swz,
                    base + 8192 + (wid << 10));
        gload_lds16(wTl + (size_t)(cb + 256 + row_s) * 512 + k0 + swz,
                    base + 16384 + (wid << 10));
    };

    stage(0, 0);
    for (int t = 0; t < 8; ++t) {
        const int buf = t & 1;
        if (t < 7) {
            stage(t + 1, buf ^ 1);
            asm volatile("s_waitcnt vmcnt(3)" ::: "memory");
        } else {
            asm volatile("s_waitcnt vmcnt(0)" ::: "memory");
        }
        __builtin_amdgcn_s_barrier();
        const unsigned char* base = lds + buf * 24576;
        __builtin_amdgcn_s_setprio(1);
        #pragma unroll
        for (int ks = 0; ks < 2; ++ks) {
            const int kb = (ks << 6) + (l4 << 4);
            bf16x8 av[2], bfv, bgv;
            #pragma unroll
            for (int fm = 0; fm < 2; ++fm) {
                int r = (wm << 5) + (fm << 4) + l15;
                av[fm] = *(const bf16x8*)(base + r * 128 + (kb ^ ((r & 7) << 4)));
            }
            {
                int n = (wn << 4) + l15;
                int o = n * 128 + (kb ^ ((n & 7) << 4));
                bfv = *(const bf16x8*)(base + 8192 + o);
                bgv = *(const bf16x8*)(base + 16384 + o);
            }
            #pragma unroll
            for (int fm = 0; fm < 2; ++fm) {
                accf[fm] = __builtin_amdgcn_mfma_f32_16x16x32_bf16(
                    av[fm], bfv, accf[fm], 0, 0, 0);
                accg[fm] = __builtin_amdgcn_mfma_f32_16x16x32_bf16(
                    av[fm], bgv, accg[fm], 0, 0, 0);
            }
        }
        __builtin_amdgcn_s_setprio(0);
        __builtin_amdgcn_s_barrier();
    }

    {
        int c = cb + (wn << 4) + l15;
        float bfb = gbias[c], bgb = gbias[c + 256];
        #pragma unroll
        for (int fm = 0; fm < 2; ++fm)
            #pragma unroll
            for (int r = 0; r < 4; ++r) {
                int m = m0 + (wm << 5) + (fm << 4) + (l4 << 2) + r;
                if (m < M) {
                    float fv = accf[fm][r] + bfb;
                    float gv = accg[fm][r] + bgb;
                    float th = 2.0f / (1.0f + __expf(-2.0f * fv)) - 1.0f;
                    float sg = 1.0f / (1.0f + __expf(-gv));
                    gated[(size_t)m * 256 + c] = (__bf16)(th * sg);
                }
            }
    }
}

// ---------------- GEMM1 narrow: grid (mt,8), BN=32, 16KB/buf -> 4 blocks/CU
// 8 waves = 4m x 2n; wave 16 rows x (16f+16g); 2 loads/thread/stage
__global__ __launch_bounds__(512, 4) void gate_n32(
    const __bf16* __restrict__ hb, __bf16* __restrict__ gated,
    const __bf16* __restrict__ wTl, const float* __restrict__ gbias,
    int tb, int dil, int M)
{
    __shared__ __align__(16) unsigned char lds[32768];
    const int tid = threadIdx.x;
    const int lane = tid & 63, wid = tid >> 6;
    const int wm = wid >> 1, wn = wid & 1;
    const int l15 = lane & 15, l4 = lane >> 4;
    const int m0 = blockIdx.x << 6;
    const int cb = blockIdx.y << 5;               // 0..224
    const int arow = (wid << 3) + (lane >> 3);    // 0..63
    const int ach = lane & 7;
    const int aswz = (ach ^ (arow & 7)) << 3;
    const int bwid = wid & 3, bhalf = wid >> 2;   // 4 waves per B half
    const int brow = (bwid << 3) + (lane >> 3);   // 0..31
    const int bswz = (ach ^ (brow & 7)) << 3;
    const int roff1 = (tb - T0) * 16;
    const int roff0 = roff1 - dil * 16;

    f32x4 accf = {}, accg = {};

    auto stage = [&](int t, int buf) {
        const int k0 = t << 6;
        const int ci0 = k0 & 255;
        const int roff = (t < 4) ? roff0 : roff1;
        unsigned char* base = lds + buf * 16384;
        int m = m0 + arow; if (m >= M) m = M - 1;
        gload_lds16(hb + (size_t)(m + roff) * 256 + ci0 + aswz,
                    base + (wid << 10));
        gload_lds16(wTl + (size_t)(cb + bhalf * 256 + brow) * 512 + k0 + bswz,
                    base + 8192 + (bhalf << 12) + (bwid << 10));
    };

    stage(0, 0);
    for (int t = 0; t < 8; ++t) {
        const int buf = t & 1;
        if (t < 7) {
            stage(t + 1, buf ^ 1);
            asm volatile("s_waitcnt vmcnt(2)" ::: "memory");
        } else {
            asm volatile("s_waitcnt vmcnt(0)" ::: "memory");
        }
        __builtin_amdgcn_s_barrier();
        const unsigned char* base = lds + buf * 16384;
        __builtin_amdgcn_s_setprio(1);
        #pragma unroll
        for (int ks = 0; ks < 2; ++ks) {
            const int kb = (ks << 6) + (l4 << 4);
            int r = (wm << 4) + l15;
            bf16x8 av = *(const bf16x8*)(base + r * 128 + (kb ^ ((r & 7) << 4)));
            int n = (wn << 4) + l15;
            int o = n * 128 + (kb ^ ((n & 7) << 4));
            bf16x8 bfv = *(const bf16x8*)(base + 8192 + o);
            bf16x8 bgv = *(const bf16x8*)(base + 12288 + o);
            accf = __builtin_amdgcn_mfma_f32_16x16x32_bf16(av, bfv, accf, 0, 0, 0);
            accg = __builtin_amdgcn_mfma_f32_16x16x32_bf16(av, bgv, accg, 0, 0, 0);
        }
        __builtin_amdgcn_s_setprio(0);
        __builtin_amdgcn_s_barrier();
    }

    {
        int c = cb + (wn << 4) + l15;
        float bfb = gbias[c], bgb = gbias[c + 256];
        #pragma unroll
        for (int r = 0; r < 4; ++r) {
            int m = m0 + (wm << 4) + (l4 << 2) + r;
            if (m < M) {
                float fv = accf[r] + bfb;
                float gv = accg[r] + bgb;
                float th = 2.0f / (1.0f + __expf(-2.0f * fv)) - 1.0f;
                float sg = 1.0f / (1.0f + __expf(-gv));
                gated[(size_t)m * 256 + c] = (__bf16)(th * sg);
            }
        }
    }
}

// ---------------- GEMM2 big (r8 + do_h): grid (mt,4)
__global__ __launch_bounds__(512, 4) void skip_v4(
    const __bf16* __restrict__ gated, const __bf16* __restrict__ w2l,
    float* __restrict__ hf, __bf16* __restrict__ hb,
    float* __restrict__ skip, const float* __restrict__ sbias,
    int tb, int M, int first, int do_h)
{
    __shared__ __align__(16) unsigned char lds[49152];
    const int tid = threadIdx.x;
    const int lane = tid & 63, wid = tid >> 6;
    const int wm = wid >> 2, wn = wid & 3;
    const int l15 = lane & 15, l4 = lane >> 4;
    const int m0 = blockIdx.x << 6;
    const int cb = blockIdx.y << 6;
    const int row_s = (wid << 3) + (lane >> 3);
    const int swz = ((lane & 7) ^ (row_s & 7)) << 3;
    const int roff1 = (tb - T0) * 16;
    const int ms0 = (TSKIP - tb) * 16;
    const bool do_s = (m0 + 64 > ms0);    // block-uniform
    const bool l3 = do_h && do_s;

    f32x4 acch[2] = {}, accs[2] = {};

    auto stage = [&](int t, int buf) {
        const int k0 = t << 6;
        unsigned char* base = lds + buf * 24576;
        int m = m0 + row_s; if (m >= M) m = M - 1;
        gload_lds16(gated + (size_t)m * 256 + k0 + swz,
                    base + (wid << 10));
        if (do_h)
            gload_lds16(w2l + (size_t)(cb + row_s) * 256 + k0 + swz,
                        base + 8192 + (wid << 10));
        if (do_s)
            gload_lds16(w2l + (size_t)(cb + 256 + row_s) * 256 + k0 + swz,
                        base + 16384 + (wid << 10));
    };

    stage(0, 0);
    for (int t = 0; t < 4; ++t) {
        const int buf = t & 1;
        if (t < 3) {
            stage(t + 1, buf ^ 1);
            if (l3) { asm volatile("s_waitcnt vmcnt(3)" ::: "memory"); }
            else    { asm volatile("s_waitcnt vmcnt(2)" ::: "memory"); }
        } else      { asm volatile("s_waitcnt vmcnt(0)" ::: "memory"); }
        __builtin_amdgcn_s_barrier();
        const unsigned char* base = lds + buf * 24576;
        __builtin_amdgcn_s_setprio(1);
        #pragma unroll
        for (int ks = 0; ks < 2; ++ks) {
            const int kb = (ks << 6) + (l4 << 4);
            bf16x8 av[2];
            #pragma unroll
            for (int fm = 0; fm < 2; ++fm) {
                int r = (wm << 5) + (fm << 4) + l15;
                av[fm] = *(const bf16x8*)(base + r * 128 + (kb ^ ((r & 7) << 4)));
            }
            int n = (wn << 4) + l15;
            int o = n * 128 + (kb ^ ((n & 7) << 4));
            if (do_h) {
                bf16x8 bhv = *(const bf16x8*)(base + 8192 + o);
                #pragma unroll
                for (int fm = 0; fm < 2; ++fm)
                    acch[fm] = __builtin_amdgcn_mfma_f32_16x16x32_bf16(
                        av[fm], bhv, acch[fm], 0, 0, 0);
            }
            if (do_s) {
                bf16x8 bsv = *(const bf16x8*)(base + 16384 + o);
                #pragma unroll
                for (int fm = 0; fm < 2; ++fm)
                    accs[fm] = __builtin_amdgcn_mfma_f32_16x16x32_bf16(
                        av[fm], bsv, accs[fm], 0, 0, 0);
            }
        }
        __builtin_amdgcn_s_setprio(0);
        __builtin_amdgcn_s_barrier();
    }

    const int soff = (tb - TSKIP) * 16;
    {
        int c = cb + (wn << 4) + l15;
        float bhb = sbias[c], bsb = sbias[c + 256];
        #pragma unroll
        for (int fm = 0; fm < 2; ++fm)
            #pragma unroll
            for (int r = 0; r < 4; ++r) {
                int m = m0 + (wm << 5) + (fm << 4) + (l4 << 2) + r;
                if (m < M) {
                    if (do_h) {
                        size_t hi = (size_t)(m + roff1) * 256 + c;
                        float hv = hf[hi] + acch[fm][r] + bhb;
                        hf[hi] = hv;
                        hb[hi] = (__bf16)hv;
                    }
                    if (do_s && m >= ms0) {
                        size_t si = (size_t)(m + soff) * 256 + c;
                        float sv = accs[fm][r] + bsb;
                        if (!first) sv += skip[si];
                        skip[si] = sv;
                    }
                }
            }
    }
}

// ---------------- GEMM2 narrow: grid (mt,8), BN=32 (layers 5,6; do_h=1)
__global__ __launch_bounds__(512, 4) void skip_n32(
    const __bf16* __restrict__ gated, const __bf16* __restrict__ w2l,
    float* __restrict__ hf, __bf16* __restrict__ hb,
    float* __restrict__ skip, const float* __restrict__ sbias,
    int tb, int M)
{
    __shared__ __align__(16) unsigned char lds[32768];
    const int tid = threadIdx.x;
    const int lane = tid & 63, wid = tid >> 6;
    const int wm = wid >> 1, wn = wid & 1;
    const int l15 = lane & 15, l4 = lane >> 4;
    const int m0 = blockIdx.x << 6;
    const int cb = blockIdx.y << 5;
    const int arow = (wid << 3) + (lane >> 3);
    const int ach = lane & 7;
    const int aswz = (ach ^ (arow & 7)) << 3;
    const int bwid = wid & 3, bhalf = wid >> 2;
    const int brow = (bwid << 3) + (lane >> 3);
    const int bswz = (ach ^ (brow & 7)) << 3;
    const int roff1 = (tb - T0) * 16;
    const int ms0 = (TSKIP - tb) * 16;
    const bool do_s = (m0 + 64 > ms0);

    f32x4 acch = {}, accs = {};

    auto stage = [&](int t, int buf) {
        const int k0 = t << 6;
        unsigned char* base = lds + buf * 16384;
        int m = m0 + arow; if (m >= M) m = M - 1;
        gload_lds16(gated + (size_t)m * 256 + k0 + aswz,
                    base + (wid << 10));
        // waves 0-3: h-half rows; waves 4-7: s-half rows (or dup h when !do_s)
        int srow = (do_s ? bhalf * 256 : 0) + cb + brow;
        gload_lds16(w2l + (size_t)srow * 256 + k0 + bswz,
                    base + 8192 + (bhalf << 12) + (bwid << 10));
    };

    stage(0, 0);
    for (int t = 0; t < 4; ++t) {
        const int buf = t & 1;
        if (t < 3) {
            stage(t + 1, buf ^ 1);
            asm volatile("s_waitcnt vmcnt(2)" ::: "memory");
        } else {
            asm volatile("s_waitcnt vmcnt(0)" ::: "memory");
        }
        __builtin_amdgcn_s_barrier();
        const unsigned char* base = lds + buf * 16384;
        __builtin_amdgcn_s_setprio(1);
        #pragma unroll
        for (int ks = 0; ks < 2; ++ks) {
            const int kb = (ks << 6) + (l4 << 4);
            int r = (wm << 4) + l15;
            bf16x8 av = *(const bf16x8*)(base + r * 128 + (kb ^ ((r & 7) << 4)));
            int n = (wn << 4) + l15;
            int o = n * 128 + (kb ^ ((n & 7) << 4));
            bf16x8 bhv = *(const bf16x8*)(base + 8192 + o);
            acch = __builtin_amdgcn_mfma_f32_16x16x32_bf16(av, bhv, acch, 0, 0, 0);
            if (do_s) {
                bf16x8 bsv = *(const bf16x8*)(base + 12288 + o);
                accs = __builtin_amdgcn_mfma_f32_16x16x32_bf16(av, bsv, accs, 0, 0, 0);
            }
        }
        __builtin_amdgcn_s_setprio(0);
        __builtin_amdgcn_s_barrier();
    }

    const int soff = (tb - TSKIP) * 16;
    {
        int c = cb + (wn << 4) + l15;
        float bhb = sbias[c], bsb = sbias[c + 256];
        #pragma unroll
        for (int r = 0; r < 4; ++r) {
            int m = m0 + (wm << 4) + (l4 << 2) + r;
            if (m < M) {
                size_t hi = (size_t)(m + roff1) * 256 + c;
                float hv = hf[hi] + acch[r] + bhb;
                hf[hi] = hv;
                hb[hi] = (__bf16)hv;
                if (do_s && m >= ms0) {
                    size_t si = (size_t)(m + soff) * 256 + c;
                    skip[si] += accs[r] + bsb;
                }
            }
        }
    }
}

// ---------------- final
__global__ void final_kernel(const float* __restrict__ skip,
                             const float* __restrict__ loc_W,
                             const float* __restrict__ loc_b,
                             const float* __restrict__ proj_W,
                             const float* __restrict__ proj_b,
                             float* __restrict__ out)
{
    int tid = threadIdx.x;
    int w = tid >> 6, lane = tid & 63;
    int o = blockIdx.x * 4 + w;          // o = l*16 + b
    int l = o >> 4, b = o & 15;
    float4 s4 = *(const float4*)&skip[((size_t)o << 8) + (lane << 2)];
    float4 w4 = *(const float4*)&loc_W[lane << 2];
    float s = s4.x * w4.x + s4.y * w4.y + s4.z * w4.z + s4.w * w4.w;
    #pragma unroll
    for (int off = 32; off; off >>= 1) s += __shfl_down(s, off);
    if (lane == 0)
        out[b * LOUT + l] = (s + loc_b[0]) * proj_W[0] + proj_b[0];
}

extern "C" void kernel_launch(void* const* d_in, const int* in_sizes, int n_in,
                              void* d_out, int out_size, void* d_ws, size_t ws_size,
                              hipStream_t stream)
{
    const float* x_lag  = (const float*)d_in[0];
    const float* x_cov  = (const float*)d_in[1];
    const float* up_W   = (const float*)d_in[2];
    const float* up_b   = (const float*)d_in[3];
    const float* dil_w  = (const float*)d_in[4];
    const float* dil_b  = (const float*)d_in[5];
    const float* skip_w = (const float*)d_in[6];
    const float* skip_b = (const float*)d_in[7];
    const float* loc_W  = (const float*)d_in[8];
    const float* loc_b  = (const float*)d_in[9];
    const float* proj_W = (const float*)d_in[10];
    const float* proj_b = (const float*)d_in[11];
    float* out = (float*)d_out;

    unsigned char* ws = (unsigned char*)d_ws;
    float*  hf   = (float*)ws;                              // 5632*256 f32
    __bf16* hb   = (__bf16*)(ws + 5767168);                 // 5632*256 bf16
    __bf16* gated= (__bf16*)(ws + 5767168 + 2883584);       // 5632*256 bf16
    float*  skip = (float*)(ws + 5767168 + 2 * 2883584);    // 1536*256 f32
    __bf16* wT   = (__bf16*)(ws + 5767168 + 2 * 2883584 + 1572864);  // 8*512*512
    __bf16* w2   = (__bf16*)((unsigned char*)wT + 4194304); // 8*512*256

    hipLaunchKernelGGL(prep_up, dim3(2048), dim3(256), 0, stream,
                       dil_w, skip_w, x_lag, x_cov, up_W, up_b, wT, w2, hf, hb);

    for (int i = 0; i < 8; ++i) {
        int dil = 1 << i;
        int tb  = T0 + 2 * dil;
        int M   = (T_TOTAL - tb) * NB;
        int mt  = (M + 63) >> 6;
        const __bf16* wTl = wT + (size_t)i * 512 * 512;
        const __bf16* w2l = w2 + (size_t)i * 512 * 256;
        const float* gb = dil_b + (size_t)i * 512;
        const float* sb = skip_b + (size_t)i * 512;

        if (i < 5)
            hipLaunchKernelGGL(gate_v4, dim3(mt, 4), dim3(512), 0, stream,
                               hb, gated, wTl, gb, tb, dil, M);
        else
            hipLaunchKernelGGL(gate_n32, dim3(mt, 8), dim3(512), 0, stream,
                               hb, gated, wTl, gb, tb, dil, M);

        if (i == 7)
            hipLaunchKernelGGL(skip_v4, dim3(mt, 4), dim3(512), 0, stream,
                               gated, w2l, hf, hb, skip, sb, tb, M, 0, 0);
        else if (i < 5)
            hipLaunchKernelGGL(skip_v4, dim3(mt, 4), dim3(512), 0, stream,
                               gated, w2l, hf, hb, skip, sb, tb, M,
                               i == 0 ? 1 : 0, 1);
        else
            hipLaunchKernelGGL(skip_n32, dim3(mt, 8), dim3(512), 0, stream,
                               gated, w2l, hf, hb, skip, sb, tb, M);
    }
    hipLaunchKernelGGL(final_kernel, dim3(LOUT * NB / 4), dim3(256), 0, stream,
                       skip, loc_W, loc_b, proj_W, proj_b, out);
}

// Round 12
// 141.912 us; speedup vs baseline: 1.9902x; 1.1157x over previous
//
#include <hip/hip_runtime.h>
#include <math.h>
#include <stdint.h>

#define T_TOTAL 2048
#define NB 16
#define D 256
#define T0 1696      // h buffer covers t in [1696, 2047]
#define TBUF 352
#define TSKIP 1952   // skip needed for t in [1952, 2047]
#define LOUT 96

typedef __bf16 bf16x8 __attribute__((ext_vector_type(8)));
typedef float f32x4 __attribute__((ext_vector_type(4)));

__device__ __forceinline__ void gload_lds16(const void* src, void* lds_dst) {
    auto g = (const __attribute__((address_space(1))) void*)(uintptr_t)src;
    auto l = (__attribute__((address_space(3))) void*)(uintptr_t)(
                 (uint32_t)(uintptr_t)lds_dst);
    __builtin_amdgcn_global_load_lds(g, l, 16, 0, 0);
}

// ---------------- fused weight prep + up-projection (one dispatch)
__global__ __launch_bounds__(256) void prep_up(
    const float* __restrict__ dil_w, const float* __restrict__ skip_w,
    const float* __restrict__ x_lag, const float* __restrict__ x_cov,
    const float* __restrict__ up_W, const float* __restrict__ up_b,
    __bf16* __restrict__ wT, __bf16* __restrict__ w2,
    float* __restrict__ hf, __bf16* __restrict__ hb)
{
    const int g0 = blockIdx.x * 256 + threadIdx.x;
    const int NT = 2048 * 256;

    for (int u = g0; u < 8 * 512 * 32; u += NT) {
        int j = u & 31;
        int cog = u >> 5;
        const float* src = dil_w + ((size_t)cog << 9) + (j << 4);
        float4 a = *(const float4*)(src);
        float4 b = *(const float4*)(src + 4);
        float4 c = *(const float4*)(src + 8);
        float4 d = *(const float4*)(src + 12);
        bf16x8 t0 = {(__bf16)a.x, (__bf16)a.z, (__bf16)b.x, (__bf16)b.z,
                     (__bf16)c.x, (__bf16)c.z, (__bf16)d.x, (__bf16)d.z};
        bf16x8 t1 = {(__bf16)a.y, (__bf16)a.w, (__bf16)b.y, (__bf16)b.w,
                     (__bf16)c.y, (__bf16)c.w, (__bf16)d.y, (__bf16)d.w};
        *(bf16x8*)(wT + ((size_t)cog << 9) + (j << 3)) = t0;
        *(bf16x8*)(wT + ((size_t)cog << 9) + 256 + (j << 3)) = t1;
    }
    for (int u = g0; u < 8 * 512 * 32; u += NT) {
        const float* src = skip_w + ((size_t)u << 3);
        float4 a = *(const float4*)(src);
        float4 b = *(const float4*)(src + 4);
        bf16x8 v = {(__bf16)a.x, (__bf16)a.y, (__bf16)a.z, (__bf16)a.w,
                    (__bf16)b.x, (__bf16)b.y, (__bf16)b.z, (__bf16)b.w};
        *(bf16x8*)(w2 + ((size_t)u << 3)) = v;
    }
    for (int u = g0; u < TBUF * NB * D; u += NT) {
        int row = u >> 8, c = u & 255;
        int tt = row >> 4, b = row & 15, t = T0 + tt;
        float acc = up_b[c] + x_lag[t * NB + b] * up_W[c];
        const float* cov = &x_cov[(t * NB + b) * 7];
        #pragma unroll
        for (int j = 0; j < 7; ++j)
            acc += cov[j] * up_W[(j + 1) * D + c];
        hf[u] = acc;
        hb[u] = (__bf16)acc;
    }
}

// ---------------- GEMM1 narrow: grid (mt,8), BN=32, 16KB/buf -> 4 blocks/CU
// 8 waves = 4m x 2n; wave 16 rows x (16f+16g); 2 loads/thread/stage
__global__ __launch_bounds__(512, 4) void gate_n32(
    const __bf16* __restrict__ hb, __bf16* __restrict__ gated,
    const __bf16* __restrict__ wTl, const float* __restrict__ gbias,
    int tb, int dil, int M)
{
    __shared__ __align__(16) unsigned char lds[32768];
    const int tid = threadIdx.x;
    const int lane = tid & 63, wid = tid >> 6;
    const int wm = wid >> 1, wn = wid & 1;
    const int l15 = lane & 15, l4 = lane >> 4;
    const int m0 = blockIdx.x << 6;
    const int cb = blockIdx.y << 5;               // 0..224
    const int arow = (wid << 3) + (lane >> 3);    // 0..63
    const int ach = lane & 7;
    const int aswz = (ach ^ (arow & 7)) << 3;
    const int bwid = wid & 3, bhalf = wid >> 2;   // 4 waves per B half
    const int brow = (bwid << 3) + (lane >> 3);   // 0..31
    const int bswz = (ach ^ (brow & 7)) << 3;
    const int roff1 = (tb - T0) * 16;
    const int roff0 = roff1 - dil * 16;

    f32x4 accf = {}, accg = {};

    auto stage = [&](int t, int buf) {
        const int k0 = t << 6;
        const int ci0 = k0 & 255;
        const int roff = (t < 4) ? roff0 : roff1;
        unsigned char* base = lds + buf * 16384;
        int m = m0 + arow; if (m >= M) m = M - 1;
        gload_lds16(hb + (size_t)(m + roff) * 256 + ci0 + aswz,
                    base + (wid << 10));
        gload_lds16(wTl + (size_t)(cb + bhalf * 256 + brow) * 512 + k0 + bswz,
                    base + 8192 + (bhalf << 12) + (bwid << 10));
    };

    stage(0, 0);
    for (int t = 0; t < 8; ++t) {
        const int buf = t & 1;
        if (t < 7) {
            stage(t + 1, buf ^ 1);
            asm volatile("s_waitcnt vmcnt(2)" ::: "memory");
        } else {
            asm volatile("s_waitcnt vmcnt(0)" ::: "memory");
        }
        __builtin_amdgcn_s_barrier();
        const unsigned char* base = lds + buf * 16384;
        __builtin_amdgcn_s_setprio(1);
        #pragma unroll
        for (int ks = 0; ks < 2; ++ks) {
            const int kb = (ks << 6) + (l4 << 4);
            int r = (wm << 4) + l15;
            bf16x8 av = *(const bf16x8*)(base + r * 128 + (kb ^ ((r & 7) << 4)));
            int n = (wn << 4) + l15;
            int o = n * 128 + (kb ^ ((n & 7) << 4));
            bf16x8 bfv = *(const bf16x8*)(base + 8192 + o);
            bf16x8 bgv = *(const bf16x8*)(base + 12288 + o);
            accf = __builtin_amdgcn_mfma_f32_16x16x32_bf16(av, bfv, accf, 0, 0, 0);
            accg = __builtin_amdgcn_mfma_f32_16x16x32_bf16(av, bgv, accg, 0, 0, 0);
        }
        __builtin_amdgcn_s_setprio(0);
        __builtin_amdgcn_s_barrier();
    }

    {
        int c = cb + (wn << 4) + l15;
        float bfb = gbias[c], bgb = gbias[c + 256];
        #pragma unroll
        for (int r = 0; r < 4; ++r) {
            int m = m0 + (wm << 4) + (l4 << 2) + r;
            if (m < M) {
                float fv = accf[r] + bfb;
                float gv = accg[r] + bgb;
                float th = 2.0f / (1.0f + __expf(-2.0f * fv)) - 1.0f;
                float sg = 1.0f / (1.0f + __expf(-gv));
                gated[(size_t)m * 256 + c] = (__bf16)(th * sg);
            }
        }
    }
}

// ---------------- GEMM2 narrow unified: grid (mt,8), BN=32
// slot0 = h-rows (or s-rows when !do_h); slot1 = s-rows (or h dup when !do_s)
__global__ __launch_bounds__(512, 4) void skip_n32(
    const __bf16* __restrict__ gated, const __bf16* __restrict__ w2l,
    float* __restrict__ hf, __bf16* __restrict__ hb,
    float* __restrict__ skip, const float* __restrict__ sbias,
    int tb, int M, int first, int do_h)
{
    __shared__ __align__(16) unsigned char lds[32768];
    const int tid = threadIdx.x;
    const int lane = tid & 63, wid = tid >> 6;
    const int wm = wid >> 1, wn = wid & 1;
    const int l15 = lane & 15, l4 = lane >> 4;
    const int m0 = blockIdx.x << 6;
    const int cb = blockIdx.y << 5;
    const int arow = (wid << 3) + (lane >> 3);
    const int ach = lane & 7;
    const int aswz = (ach ^ (arow & 7)) << 3;
    const int bwid = wid & 3, bhalf = wid >> 2;
    const int brow = (bwid << 3) + (lane >> 3);
    const int bswz = (ach ^ (brow & 7)) << 3;
    const int roff1 = (tb - T0) * 16;
    const int ms0 = (TSKIP - tb) * 16;
    const bool do_s = (m0 + 64 > ms0);
    const int slot0base = do_h ? 0 : 256;          // rows staged into slot0
    const int slot1base = do_s ? 256 : 0;          // rows staged into slot1
    const int s_lds = do_h ? 12288 : 8192;         // accs read slot

    f32x4 acch = {}, accs = {};

    auto stage = [&](int t, int buf) {
        const int k0 = t << 6;
        unsigned char* base = lds + buf * 16384;
        int m = m0 + arow; if (m >= M) m = M - 1;
        gload_lds16(gated + (size_t)m * 256 + k0 + aswz,
                    base + (wid << 10));
        int rowb = bhalf ? slot1base : slot0base;
        gload_lds16(w2l + (size_t)(rowb + cb + brow) * 256 + k0 + bswz,
                    base + 8192 + (bhalf << 12) + (bwid << 10));
    };

    stage(0, 0);
    for (int t = 0; t < 4; ++t) {
        const int buf = t & 1;
        if (t < 3) {
            stage(t + 1, buf ^ 1);
            asm volatile("s_waitcnt vmcnt(2)" ::: "memory");
        } else {
            asm volatile("s_waitcnt vmcnt(0)" ::: "memory");
        }
        __builtin_amdgcn_s_barrier();
        const unsigned char* base = lds + buf * 16384;
        __builtin_amdgcn_s_setprio(1);
        #pragma unroll
        for (int ks = 0; ks < 2; ++ks) {
            const int kb = (ks << 6) + (l4 << 4);
            int r = (wm << 4) + l15;
            bf16x8 av = *(const bf16x8*)(base + r * 128 + (kb ^ ((r & 7) << 4)));
            int n = (wn << 4) + l15;
            int o = n * 128 + (kb ^ ((n & 7) << 4));
            if (do_h) {
                bf16x8 bhv = *(const bf16x8*)(base + 8192 + o);
                acch = __builtin_amdgcn_mfma_f32_16x16x32_bf16(av, bhv, acch, 0, 0, 0);
            }
            if (do_s) {
                bf16x8 bsv = *(const bf16x8*)(base + s_lds + o);
                accs = __builtin_amdgcn_mfma_f32_16x16x32_bf16(av, bsv, accs, 0, 0, 0);
            }
        }
        __builtin_amdgcn_s_setprio(0);
        __builtin_amdgcn_s_barrier();
    }

    const int soff = (tb - TSKIP) * 16;
    {
        int c = cb + (wn << 4) + l15;
        float bhb = sbias[c], bsb = sbias[c + 256];
        #pragma unroll
        for (int r = 0; r < 4; ++r) {
            int m = m0 + (wm << 4) + (l4 << 2) + r;
            if (m < M) {
                if (do_h) {
                    size_t hi = (size_t)(m + roff1) * 256 + c;
                    float hv = hf[hi] + acch[r] + bhb;
                    hf[hi] = hv;
                    hb[hi] = (__bf16)hv;
                }
                if (do_s && m >= ms0) {
                    size_t si = (size_t)(m + soff) * 256 + c;
                    float sv = accs[r] + bsb;
                    if (!first) sv += skip[si];
                    skip[si] = sv;
                }
            }
        }
    }
}

// ---------------- final
__global__ void final_kernel(const float* __restrict__ skip,
                             const float* __restrict__ loc_W,
                             const float* __restrict__ loc_b,
                             const float* __restrict__ proj_W,
                             const float* __restrict__ proj_b,
                             float* __restrict__ out)
{
    int tid = threadIdx.x;
    int w = tid >> 6, lane = tid & 63;
    int o = blockIdx.x * 4 + w;          // o = l*16 + b
    int l = o >> 4, b = o & 15;
    float4 s4 = *(const float4*)&skip[((size_t)o << 8) + (lane << 2)];
    float4 w4 = *(const float4*)&loc_W[lane << 2];
    float s = s4.x * w4.x + s4.y * w4.y + s4.z * w4.z + s4.w * w4.w;
    #pragma unroll
    for (int off = 32; off; off >>= 1) s += __shfl_down(s, off);
    if (lane == 0)
        out[b * LOUT + l] = (s + loc_b[0]) * proj_W[0] + proj_b[0];
}

extern "C" void kernel_launch(void* const* d_in, const int* in_sizes, int n_in,
                              void* d_out, int out_size, void* d_ws, size_t ws_size,
                              hipStream_t stream)
{
    const float* x_lag  = (const float*)d_in[0];
    const float* x_cov  = (const float*)d_in[1];
    const float* up_W   = (const float*)d_in[2];
    const float* up_b   = (const float*)d_in[3];
    const float* dil_w  = (const float*)d_in[4];
    const float* dil_b  = (const float*)d_in[5];
    const float* skip_w = (const float*)d_in[6];
    const float* skip_b = (const float*)d_in[7];
    const float* loc_W  = (const float*)d_in[8];
    const float* loc_b  = (const float*)d_in[9];
    const float* proj_W = (const float*)d_in[10];
    const float* proj_b = (const float*)d_in[11];
    float* out = (float*)d_out;

    unsigned char* ws = (unsigned char*)d_ws;
    float*  hf   = (float*)ws;                              // 5632*256 f32
    __bf16* hb   = (__bf16*)(ws + 5767168);                 // 5632*256 bf16
    __bf16* gated= (__bf16*)(ws + 5767168 + 2883584);       // 5632*256 bf16
    float*  skip = (float*)(ws + 5767168 + 2 * 2883584);    // 1536*256 f32
    __bf16* wT   = (__bf16*)(ws + 5767168 + 2 * 2883584 + 1572864);  // 8*512*512
    __bf16* w2   = (__bf16*)((unsigned char*)wT + 4194304); // 8*512*256

    hipLaunchKernelGGL(prep_up, dim3(2048), dim3(256), 0, stream,
                       dil_w, skip_w, x_lag, x_cov, up_W, up_b, wT, w2, hf, hb);

    for (int i = 0; i < 8; ++i) {
        int dil = 1 << i;
        int tb  = T0 + 2 * dil;
        int M   = (T_TOTAL - tb) * NB;
        int mt  = (M + 63) >> 6;
        const __bf16* wTl = wT + (size_t)i * 512 * 512;
        const __bf16* w2l = w2 + (size_t)i * 512 * 256;
        const float* gb = dil_b + (size_t)i * 512;
        const float* sb = skip_b + (size_t)i * 512;

        hipLaunchKernelGGL(gate_n32, dim3(mt, 8), dim3(512), 0, stream,
                           hb, gated, wTl, gb, tb, dil, M);
        hipLaunchKernelGGL(skip_n32, dim3(mt, 8), dim3(512), 0, stream,
                           gated, w2l, hf, hb, skip, sb, tb, M,
                           i == 0 ? 1 : 0, i == 7 ? 0 : 1);
    }
    hipLaunchKernelGGL(final_kernel, dim3(LOUT * NB / 4), dim3(256), 0, stream,
                       skip, loc_W, loc_b, proj_W, proj_b, out);
}